// Round 3
// baseline (522.422 us; speedup 1.0000x reference)
//
#include <hip/hip_runtime.h>
#include <hip/hip_bf16.h>

#define HW 112
#define HWHW 12544           // 112*112
#define NB 32
#define CIN 64
#define G 4
#define IN_G 16
#define OUT_G 32
#define NC (NB * G * OUT_G)  // 4096 output planes

typedef _Float16 f16;
typedef _Float16 f16x8 __attribute__((ext_vector_type(8)));
typedef _Float16 f16x4 __attribute__((ext_vector_type(4)));
typedef float f32x4 __attribute__((ext_vector_type(4)));

// ---------- float <-> ordered uint encoding for atomic min/max ----------
__device__ __forceinline__ unsigned enc_f32(float f) {
    unsigned u = __float_as_uint(f);
    return (u & 0x80000000u) ? ~u : (u | 0x80000000u);
}
__device__ __forceinline__ float dec_f32(unsigned k) {
    unsigned u = (k & 0x80000000u) ? (k & 0x7fffffffu) : ~k;
    return __uint_as_float(u);
}

// ---------- init: mm slots + zero stats ----------
__global__ __launch_bounds__(256) void init_kernel(unsigned* __restrict__ mm,
                                                   float* __restrict__ stats) {
    int i = blockIdx.x * 256 + threadIdx.x;
    if (i < 2 * NC) stats[i] = 0.0f;
    if (blockIdx.x == 0 && threadIdx.x < 2 * G)
        mm[threadIdx.x] = (threadIdx.x & 1) ? 0u : 0xFFFFFFFFu;
}

// ---------- per-group min/max: one block per (n,c) plane ----------
__global__ __launch_bounds__(256) void minmax_kernel(const float* __restrict__ x,
                                                     unsigned* __restrict__ mm) {
    const int pc = blockIdx.x;               // 0..2047
    const int g = (pc & 63) >> 4;
    const float* p = x + (size_t)pc * HWHW;
    float lmin = 3.4e38f, lmax = -3.4e38f;
    for (int i = threadIdx.x; i < HWHW / 4; i += 256) {
        float4 v = ((const float4*)p)[i];
        lmin = fminf(lmin, fminf(fminf(v.x, v.y), fminf(v.z, v.w)));
        lmax = fmaxf(lmax, fmaxf(fmaxf(v.x, v.y), fmaxf(v.z, v.w)));
    }
    for (int o = 32; o > 0; o >>= 1) {
        lmin = fminf(lmin, __shfl_down(lmin, o));
        lmax = fmaxf(lmax, __shfl_down(lmax, o));
    }
    __shared__ float smn[4], smx[4];
    int wid = threadIdx.x >> 6, lane = threadIdx.x & 63;
    if (lane == 0) { smn[wid] = lmin; smx[wid] = lmax; }
    __syncthreads();
    if (threadIdx.x == 0) {
        float m0 = fminf(fminf(smn[0], smn[1]), fminf(smn[2], smn[3]));
        float m1 = fmaxf(fmaxf(smx[0], smx[1]), fmaxf(smx[2], smx[3]));
        atomicMin(&mm[2 * g],     enc_f32(m0));
        atomicMax(&mm[2 * g + 1], enc_f32(m1));
    }
}

// ---------- fold base+poly weights into powers-of-x basis, f16, linear ----------
// Wf layout: (((g*2+h)*9 + tap)*32 + co)*32 + (ci_local*4 + d),  h = ci>>3
__global__ __launch_bounds__(256) void fold_kernel(const float* __restrict__ bw,
                                                   const float* __restrict__ pw,
                                                   const unsigned* __restrict__ mm,
                                                   f16* __restrict__ Wf) {
    int idx = blockIdx.x * 256 + threadIdx.x;           // (g, co, ci, tap)
    if (idx >= G * OUT_G * IN_G * 9) return;
    int g  = idx / (OUT_G * IN_G * 9);
    int r  = idx - g * (OUT_G * IN_G * 9);
    int co = r / (IN_G * 9);
    int r2 = r - co * (IN_G * 9);
    int ci = r2 / 9, tap = r2 - (r2 / 9) * 9;

    const float mn = dec_f32(mm[2 * g]);
    const float mx = dec_f32(mm[2 * g + 1]);
    const float a = 2.0f / (mx - mn);
    const float b = -a * mn - 1.0f;

    const float bwv = bw[((g * OUT_G + co) * IN_G + ci) * 9 + tap];
    const float* pwb = pw + (size_t)(g * OUT_G + co) * 64 * 9;
    const float p0 = pwb[(0  + ci) * 9 + tap];
    const float p1 = pwb[(16 + ci) * 9 + tap];
    const float p2 = pwb[(32 + ci) * 9 + tap];
    const float p3 = pwb[(48 + ci) * 9 + tap];

    const float W0 = p0 + p1 * b + p2 * (1.5f * b * b - 0.5f) + p3 * (2.5f * b * b * b - 1.5f * b);
    const float W1 = bwv + p1 * a + p2 * (3.0f * a * b) + p3 * (7.5f * a * b * b - 1.5f * a);
    const float W2 = p2 * (1.5f * a * a) + p3 * (7.5f * a * a * b);
    const float W3 = p3 * (2.5f * a * a * a);

    const int h = ci >> 3, cil = ci & 7;
    f16x4 v; v[0] = (f16)W0; v[1] = (f16)W1; v[2] = (f16)W2; v[3] = (f16)W3;
    size_t off = ((size_t)(((g * 2 + h) * 9 + tap) * OUT_G + co)) * 32 + cil * 4;
    *(f16x4*)(Wf + off) = v;
}

// LDS swizzle: physical 16B-unit = logical ^ (p&3) ^ ((p>>2)&1)  (balanced R+W)
__device__ __forceinline__ int swz(int p, int u) {
    return p * 64 + ((u ^ (p & 3) ^ ((p >> 2) & 1)) << 4);
}

// ---------- MFMA implicit-GEMM conv, K split in 2 halves, fused stats ----------
// grid (49, 4, 32), block 256 = 4 waves; tile 16x16 px, all 32 co.
__global__ __launch_bounds__(256) void conv_mfma(const float* __restrict__ x,
                                                 const f16* __restrict__ Wf,
                                                 float* __restrict__ out,
                                                 float* __restrict__ stats) {
    const int tile = blockIdx.x, g = blockIdx.y, n = blockIdx.z;
    const int ty0 = (tile / 7) * 16, tx0 = (tile % 7) * 16;

    __shared__ __align__(16) char As[324 * 64];     // 20736 B: 18x18 px, 32 f16 each
    __shared__ float sred[2][32];

    const int tid = threadIdx.x;
    const int l = tid & 63, w = tid >> 6;
    const int lx = l & 15, qu = l >> 4;

    if (tid < 64) ((float*)sred)[tid] = 0.0f;

    const float* xg = x + ((size_t)n * CIN + g * IN_G) * HWHW;
    const f16* WfG = Wf + (size_t)g * 2 * 9 * 1024;

    f32x4 acc[4][2];
#pragma unroll
    for (int rr = 0; rr < 4; ++rr)
#pragma unroll
        for (int c = 0; c < 2; ++c) acc[rr][c] = (f32x4)0.0f;

#pragma unroll
    for (int h = 0; h < 2; ++h) {
        // B preload: 18 fragments from global (L1-resident, coalesced 1KB/frag-set)
        f16x8 B[9][2];
#pragma unroll
        for (int t = 0; t < 9; ++t)
#pragma unroll
            for (int c = 0; c < 2; ++c)
                B[t][c] = *(const f16x8*)(WfG + ((size_t)((h * 9 + t) * 32 + c * 16 + lx)) * 32 + qu * 8);

        // stage A half: 324 px x 4 ci-pairs, pack [1,x,x2,x3] for 2 ci per item
        for (int it = 0; it < 6; ++it) {
            int j = tid + it * 256;
            if (j < 1296) {
                int cip = j / 324, p = j - cip * 324;
                int py = p / 18, px_ = p - py * 18;
                int gy = ty0 + py - 1, gx = tx0 + px_ - 1;
                bool ok = (gy >= 0) & (gy < HW) & (gx >= 0) & (gx < HW);
                const float* src = xg + (size_t)(h * 8 + 2 * cip) * HWHW + gy * HW + gx;
                float v0 = ok ? src[0] : 0.0f;
                float v1 = ok ? src[HWHW] : 0.0f;
                f16 one = ok ? (f16)1.0f : (f16)0.0f;
                f16x8 pk;
                pk[0] = one; pk[1] = (f16)v0; pk[2] = (f16)(v0 * v0); pk[3] = (f16)(v0 * v0 * v0);
                pk[4] = one; pk[5] = (f16)v1; pk[6] = (f16)(v1 * v1); pk[7] = (f16)(v1 * v1 * v1);
                *(f16x8*)(&As[swz(p, cip)]) = pk;
            }
        }
        __syncthreads();

        // compute: A-row reuse across kh
#pragma unroll
        for (int kw = 0; kw < 3; ++kw) {
            f16x8 a[6];
#pragma unroll
            for (int r = 0; r < 6; ++r) {
                int pl = (4 * w + r) * 18 + lx + kw;
                a[r] = *(const f16x8*)(&As[swz(pl, qu)]);
            }
#pragma unroll
            for (int r = 0; r < 6; ++r)
#pragma unroll
                for (int kh = 0; kh < 3; ++kh) {
                    const int rr = r - kh;
                    if (rr >= 0 && rr < 4) {
                        acc[rr][0] = __builtin_amdgcn_mfma_f32_16x16x32_f16(a[r], B[kh * 3 + kw][0], acc[rr][0], 0, 0, 0);
                        acc[rr][1] = __builtin_amdgcn_mfma_f32_16x16x32_f16(a[r], B[kh * 3 + kw][1], acc[rr][1], 0, 0, 0);
                    }
                }
        }
        __syncthreads();   // safe to restage (h=0) / start stats LDS phase (h=1)
    }

    // ---- fused stats: per-co sum & sumsq over this tile ----
    float s0 = 0.f, ss0 = 0.f, s1 = 0.f, ss1 = 0.f;
#pragma unroll
    for (int rr = 0; rr < 4; ++rr)
#pragma unroll
        for (int j = 0; j < 4; ++j) {
            float v0 = acc[rr][0][j], v1 = acc[rr][1][j];
            s0 += v0; ss0 += v0 * v0;
            s1 += v1; ss1 += v1 * v1;
        }
    s0 += __shfl_xor(s0, 16); ss0 += __shfl_xor(ss0, 16);
    s0 += __shfl_xor(s0, 32); ss0 += __shfl_xor(ss0, 32);
    s1 += __shfl_xor(s1, 16); ss1 += __shfl_xor(ss1, 16);
    s1 += __shfl_xor(s1, 32); ss1 += __shfl_xor(ss1, 32);
    if (qu == 0) {
        atomicAdd(&sred[0][lx],      s0); atomicAdd(&sred[1][lx],      ss0);
        atomicAdd(&sred[0][16 + lx], s1); atomicAdd(&sred[1][16 + lx], ss1);
    }

    // ---- store conv output (pre-norm) ----
    const size_t ob = ((size_t)n * (G * OUT_G) + g * OUT_G) * HWHW;
#pragma unroll
    for (int rr = 0; rr < 4; ++rr) {
        const int y = ty0 + 4 * w + rr;
#pragma unroll
        for (int c = 0; c < 2; ++c) {
            float* dst = out + ob + (size_t)(c * 16 + lx) * HWHW + (size_t)y * HW + tx0 + qu * 4;
            *(f32x4*)dst = acc[rr][c];
        }
    }

    __syncthreads();
    if (tid < 32) {
        const size_t slot = (size_t)n * (G * OUT_G) + g * OUT_G + tid;
        atomicAdd(&stats[slot * 2],     sred[0][tid]);
        atomicAdd(&stats[slot * 2 + 1], sred[1][tid]);
    }
}

// ---------- apply: instance norm + SiLU, pure elementwise ----------
__global__ __launch_bounds__(256) void apply_kernel(float* __restrict__ out,
                                                    const float* __restrict__ stats) {
    const int nc = blockIdx.x;
    const float s  = stats[nc * 2];
    const float ss = stats[nc * 2 + 1];
    const float mu = s * (1.0f / HWHW);
    const float rs = rsqrtf(ss * (1.0f / HWHW) - mu * mu + 1e-5f);
    float* p = out + (size_t)nc * HWHW;
    for (int i = threadIdx.x; i < HWHW / 4; i += 256) {
        float4 v = ((const float4*)p)[i];
        v.x = (v.x - mu) * rs; v.x = v.x / (1.0f + __expf(-v.x));
        v.y = (v.y - mu) * rs; v.y = v.y / (1.0f + __expf(-v.y));
        v.z = (v.z - mu) * rs; v.z = v.z / (1.0f + __expf(-v.z));
        v.w = (v.w - mu) * rs; v.w = v.w / (1.0f + __expf(-v.w));
        ((float4*)p)[i] = v;
    }
}

extern "C" void kernel_launch(void* const* d_in, const int* in_sizes, int n_in,
                              void* d_out, int out_size, void* d_ws, size_t ws_size,
                              hipStream_t stream) {
    const float* x  = (const float*)d_in[0];
    const float* bw = (const float*)d_in[1];
    const float* pw = (const float*)d_in[2];
    float* out = (float*)d_out;

    unsigned* mm = (unsigned*)d_ws;                       // 32 B
    float* stats = (float*)((char*)d_ws + 1024);          // 8192 f32 = 32768 B
    f16* Wf = (f16*)((char*)d_ws + 34816);                // 147456 B

    init_kernel<<<32, 256, 0, stream>>>(mm, stats);
    minmax_kernel<<<NB * CIN, 256, 0, stream>>>(x, mm);
    fold_kernel<<<144, 256, 0, stream>>>(bw, pw, mm, Wf);
    conv_mfma<<<dim3(49, G, NB), 256, 0, stream>>>(x, Wf, out, stats);
    apply_kernel<<<NC, 256, 0, stream>>>(out, stats);
}